// Round 4
// baseline (167.855 us; speedup 1.0000x reference)
//
#include <hip/hip_runtime.h>

#define LL   2048
#define BB   4
#define DD   512
#define HH   8
#define DKK  64
#define WBAND 12
#define NBAND 25   // 2*WBAND+1

typedef __attribute__((ext_vector_type(8))) short  bf16x8;
typedef __attribute__((ext_vector_type(4))) float  f32x4;

static __device__ __forceinline__ float bf2f(unsigned short u) {
    union { unsigned int i; float f; } c; c.i = ((unsigned int)u) << 16; return c.f;
}
static __device__ __forceinline__ unsigned short f2bf(float f) {
    union { float f; unsigned int i; } c; c.f = f;
    unsigned int x = c.i;
    return (unsigned short)((x + 0x7fffu + ((x >> 16) & 1u)) >> 16);  // RNE
}
static __device__ __forceinline__ bf16x8 pack8(float4 x0, float4 x1) {
    bf16x8 r;
    r[0] = (short)f2bf(x0.x); r[1] = (short)f2bf(x0.y);
    r[2] = (short)f2bf(x0.z); r[3] = (short)f2bf(x0.w);
    r[4] = (short)f2bf(x1.x); r[5] = (short)f2bf(x1.y);
    r[6] = (short)f2bf(x1.z); r[7] = (short)f2bf(x1.w);
    return r;
}

// ---------------------------------------------------------------------------
// proj: Out[b,h,l,dk] = ((X @ Wm^T)[m,n] + bias[n]) * scale, stored bf16.
// ---------------------------------------------------------------------------
__global__ __launch_bounds__(256) void proj_mfma(
    const float* __restrict__ X, const float* __restrict__ Wm,
    const float* __restrict__ bias, unsigned short* __restrict__ Out,
    float scale)
{
    const int t  = threadIdx.x;
    const int w  = t >> 6;
    const int l  = t & 63;
    const int mb = blockIdx.x * 128 + (w >> 1) * 64;
    const int nb = blockIdx.y * 128 + (w & 1) * 64;
    const int lr = l & 15;
    const int lk = (l >> 4) * 8;

    f32x4 acc[4][4] = {};

    for (int ks = 0; ks < DD; ks += 32) {
        bf16x8 a[4], b[4];
#pragma unroll
        for (int mi = 0; mi < 4; ++mi) {
            const float* p = &X[(size_t)(mb + 16 * mi + lr) * DD + ks + lk];
            a[mi] = pack8(*(const float4*)p, *(const float4*)(p + 4));
        }
#pragma unroll
        for (int ni = 0; ni < 4; ++ni) {
            const float* p = &Wm[(size_t)(nb + 16 * ni + lr) * DD + ks + lk];
            b[ni] = pack8(*(const float4*)p, *(const float4*)(p + 4));
        }
#pragma unroll
        for (int mi = 0; mi < 4; ++mi)
#pragma unroll
            for (int ni = 0; ni < 4; ++ni)
                acc[mi][ni] = __builtin_amdgcn_mfma_f32_16x16x32_bf16(
                    a[mi], b[ni], acc[mi][ni], 0, 0, 0);
    }

#pragma unroll
    for (int mi = 0; mi < 4; ++mi)
#pragma unroll
        for (int j = 0; j < 4; ++j) {
            const int m    = mb + 16 * mi + (l >> 4) * 4 + j;
            const int lseq = m >> 2;
            const int bidx = m & 3;
#pragma unroll
            for (int ni = 0; ni < 4; ++ni) {
                const int n  = nb + 16 * ni + lr;
                const int h  = n >> 6;
                const int dk = n & 63;
                const float val = (acc[mi][ni][j] + bias[n]) * scale;
                Out[(((size_t)(bidx * HH + h)) * LL + lseq) * DKK + dk] = f2bf(val);
            }
        }
}

// ---------------------------------------------------------------------------
// scorez: Z[bh,q] = sum_k exp( Qh[bh,q] . Kh[bh,k] )   (Q pre-scaled by 1/8)
// ---------------------------------------------------------------------------
__global__ __launch_bounds__(256) void scorez_mfma(
    const unsigned short* __restrict__ Qh, const unsigned short* __restrict__ Kh,
    float* __restrict__ Z)
{
    __shared__ float Zp[4][64];
    const int t  = threadIdx.x;
    const int w  = t >> 6;
    const int l  = t & 63;
    const int bh = blockIdx.y;
    const int qb = blockIdx.x * 64;
    const int lr = l & 15;
    const int lk = (l >> 4) * 8;
    const unsigned short* Qp = Qh + (size_t)bh * LL * DKK;
    const unsigned short* Kp = Kh + (size_t)bh * LL * DKK;

    bf16x8 qa[4][2];
#pragma unroll
    for (int r = 0; r < 4; ++r)
#pragma unroll
        for (int s = 0; s < 2; ++s)
            qa[r][s] = *(const bf16x8*)&Qp[(size_t)(qb + 16 * r + lr) * DKK + 32 * s + lk];

    float zacc[4][4] = {};
    const int k0 = w * 512;
    for (int kt = k0; kt < k0 + 512; kt += 16) {
        const bf16x8 kb0 = *(const bf16x8*)&Kp[(size_t)(kt + lr) * DKK + lk];
        const bf16x8 kb1 = *(const bf16x8*)&Kp[(size_t)(kt + lr) * DKK + 32 + lk];
#pragma unroll
        for (int r = 0; r < 4; ++r) {
            f32x4 acc = {0.f, 0.f, 0.f, 0.f};
            acc = __builtin_amdgcn_mfma_f32_16x16x32_bf16(qa[r][0], kb0, acc, 0, 0, 0);
            acc = __builtin_amdgcn_mfma_f32_16x16x32_bf16(qa[r][1], kb1, acc, 0, 0, 0);
#pragma unroll
            for (int j = 0; j < 4; ++j)
                zacc[r][j] += __expf(acc[j]);
        }
    }

#pragma unroll
    for (int m = 8; m >= 1; m >>= 1)
#pragma unroll
        for (int r = 0; r < 4; ++r)
#pragma unroll
            for (int j = 0; j < 4; ++j)
                zacc[r][j] += __shfl_xor(zacc[r][j], m, 64);

    if (lr == 0) {
#pragma unroll
        for (int r = 0; r < 4; ++r)
#pragma unroll
            for (int j = 0; j < 4; ++j)
                Zp[w][16 * r + (l >> 4) * 4 + j] = zacc[r][j];
    }
    __syncthreads();
    if (t < 64)
        Z[(size_t)bh * LL + qb + t] = Zp[0][t] + Zp[1][t] + Zp[2][t] + Zp[3][t];
}

// ---------------------------------------------------------------------------
// weights: one WAVE per (b,q). lane l: h = l>>3, jslot = l&7, j = jslot+8c.
// Head-sum via shfl_xor {8,16,32}; band-sum via shfl_xor {1,2,4}. No LDS,
// no barriers. Writes compact wgt[(b*L+q)*32 + j].
// ---------------------------------------------------------------------------
__global__ __launch_bounds__(256) void weights_kernel(
    const unsigned short* __restrict__ Qh, const unsigned short* __restrict__ Kh,
    const float* __restrict__ Z, float* __restrict__ wgtbuf)
{
    const int t = threadIdx.x;
    const int w = t >> 6;
    const int l = t & 63;
    const int idx = blockIdx.x * 4 + w;       // idx = b*L + q
    const int b = idx >> 11;
    const int q = idx & 2047;
    const int h = l >> 3;
    const int jslot = l & 7;

    // preload Q row for this lane's head
    bf16x8 qv[8];
    {
        const bf16x8* qp = (const bf16x8*)&Qh[(((size_t)b * HH + h) * LL + q) * DKK];
#pragma unroll
        for (int i = 0; i < 8; ++i) qv[i] = qp[i];
    }
    const float zinv = 1.0f / Z[((size_t)b * HH + h) * LL + q];

    float e[4];
#pragma unroll
    for (int c = 0; c < 4; ++c) {
        const int j = jslot + 8 * c;
        const int k = q - WBAND + j;
        float a = 0.f;
        if (j < NBAND && k >= 0 && k < LL) {
            const bf16x8* kp = (const bf16x8*)&Kh[(((size_t)b * HH + h) * LL + k) * DKK];
            float s = 0.f;
#pragma unroll
            for (int i = 0; i < 8; ++i) {
                const bf16x8 ka = kp[i];
#pragma unroll
                for (int ee = 0; ee < 8; ++ee)
                    s += bf2f((unsigned short)qv[i][ee]) * bf2f((unsigned short)ka[ee]);
            }
            a = __expf(s) * zinv;
        }
        e[c] = a;
    }

    // sum over heads (lane bits 3,4,5)
#pragma unroll
    for (int m = 8; m <= 32; m <<= 1)
#pragma unroll
        for (int c = 0; c < 4; ++c)
            e[c] += __shfl_xor(e[c], m, 64);

    // * dist, then band-sum over jslot (lane bits 0,1,2)
    float att[4];
    float part = 0.f;
#pragma unroll
    for (int c = 0; c < 4; ++c) {
        const int j = jslot + 8 * c;
        const float dd = (float)(j - WBAND);
        att[c] = (j < NBAND) ? e[c] * __expf(-0.5f * dd * dd) : 0.f;
        part += att[c];
    }
#pragma unroll
    for (int m = 1; m <= 4; m <<= 1)
        part += __shfl_xor(part, m, 64);
    const float winv = 1.0f / part;

    if (h == 0) {
#pragma unroll
        for (int c = 0; c < 4; ++c) {
            const int j = jslot + 8 * c;
            if (j < NBAND)
                wgtbuf[(size_t)idx * 32 + j] = att[c] * winv;
        }
    }
}

// ---------------------------------------------------------------------------
// woutout: grid (L/8, B). Per block: 8 q rows for one b.
//   phase 1: LDS-load wgt[8][25]
//   phase 2: stream full wout rows (67 MB total) with NT f32x4 stores
//   phase 3: out[q,b,:] via register sliding window over 28 v rows
// ---------------------------------------------------------------------------
__global__ __launch_bounds__(256) void woutout_kernel(
    const float* __restrict__ wgtbuf, const float* __restrict__ v,
    float* __restrict__ out, float* __restrict__ wout)
{
    __shared__ float lw[8][NBAND];
    const int t  = threadIdx.x;
    const int q0 = blockIdx.x * 8;
    const int b  = blockIdx.y;

    if (t < 8 * NBAND) {
        const int qq = t / NBAND;
        const int j  = t - qq * NBAND;
        lw[qq][j] = wgtbuf[((size_t)b * LL + q0 + qq) * 32 + j];
    }
    __syncthreads();

    // ---- wout: 8 rows x 512 f32x4 = 4096 f4, 16 per thread ----
#pragma unroll
    for (int r = 0; r < 16; ++r) {
        const int flat = t + 256 * r;
        const int qq = flat >> 9;
        const int c4 = flat & 511;
        const int q  = q0 + qq;
        const int c  = c4 * 4;
        f32x4 vw = {0.f, 0.f, 0.f, 0.f};
        const int dlo = c - q + WBAND;          // j of element e=0
        if (dlo >= -3 && dlo < NBAND) {         // any overlap with band
#pragma unroll
            for (int e = 0; e < 4; ++e) {
                const int d = dlo + e;
                if (d >= 0 && d < NBAND) vw[e] = lw[qq][d];
            }
        }
        __builtin_nontemporal_store(vw, (f32x4*)&wout[((size_t)b * LL + q) * LL + c]);
    }

    // ---- out: thread t -> qsub = t>>7 (4 q each), d4 = t&127 ----
    {
        const int qsub = t >> 7;
        const int d4   = t & 127;
        const int qs   = q0 + qsub * 4;
        const int kbase = qs - WBAND;
        f32x4 acc[4] = {{0,0,0,0},{0,0,0,0},{0,0,0,0},{0,0,0,0}};
#pragma unroll
        for (int kk = 0; kk < 28; ++kk) {
            const int k = kbase + kk;
            f32x4 vv = {0.f, 0.f, 0.f, 0.f};
            if (k >= 0 && k < LL)
                vv = *(const f32x4*)&v[((size_t)k * BB + b) * DD + d4 * 4];
#pragma unroll
            for (int qi = 0; qi < 4; ++qi) {
                const int j = kk - qi;
                if (j >= 0 && j < NBAND) {
                    const float wv = lw[qsub * 4 + qi][j];
                    acc[qi][0] += wv * vv[0]; acc[qi][1] += wv * vv[1];
                    acc[qi][2] += wv * vv[2]; acc[qi][3] += wv * vv[3];
                }
            }
        }
#pragma unroll
        for (int qi = 0; qi < 4; ++qi) {
            const int q = qs + qi;
            __builtin_nontemporal_store(acc[qi],
                (f32x4*)&out[((size_t)q * BB + b) * DD + d4 * 4]);
        }
    }
}

// ---------------------------------------------------------------------------
extern "C" void kernel_launch(void* const* d_in, const int* in_sizes, int n_in,
                              void* d_out, int out_size, void* d_ws, size_t ws_size,
                              hipStream_t stream) {
    const float* q  = (const float*)d_in[0];
    const float* k  = (const float*)d_in[1];
    const float* v  = (const float*)d_in[2];
    const float* Wq = (const float*)d_in[3];
    const float* bq = (const float*)d_in[4];
    const float* Wk = (const float*)d_in[5];
    const float* bk = (const float*)d_in[6];

    float* out  = (float*)d_out;                       // [L,B,D]
    float* wout = out + (size_t)LL * BB * DD;          // [B,L,L]

    unsigned short* Qh = (unsigned short*)d_ws;                 // bf16 [B,H,L,DK] 8 MB
    unsigned short* Kh = Qh + (size_t)BB * HH * LL * DKK;       // bf16 [B,H,L,DK] 8 MB
    float* Z      = (float*)(Kh + (size_t)BB * HH * LL * DKK);  // [B*H*L] 256 KB
    float* wgtbuf = Z + (size_t)BB * HH * LL;                   // [B*L][32] 1 MB

    dim3 gp(LL * BB / 128, DD / 128);                  // 64 x 4
    proj_mfma<<<gp, 256, 0, stream>>>(q, Wq, bq, Qh, 0.125f);  // Q pre-scaled 1/8
    proj_mfma<<<gp, 256, 0, stream>>>(k, Wk, bk, Kh, 1.0f);

    scorez_mfma<<<dim3(LL / 64, BB * HH), 256, 0, stream>>>(Qh, Kh, Z);

    weights_kernel<<<BB * LL / 4, 256, 0, stream>>>(Qh, Kh, Z, wgtbuf);

    woutout_kernel<<<dim3(LL / 8, BB), 256, 0, stream>>>(wgtbuf, v, out, wout);
}